// Round 3
// baseline (276.121 us; speedup 1.0000x reference)
//
#include <hip/hip_runtime.h>
#include <hip/hip_cooperative_groups.h>

namespace cg = cooperative_groups;

// CriticGCN: out = D^-1/2 (A+I) D^-1/2 (x W1) + b1, then @ W_head + b_head.
// Head folded through the (linear) aggregation:
//   w = W1 @ W_head (100 floats), c = b1.W_head + b_head
//   s[i] = x[i].w ; dinv[i] = rsqrt(deg[i]+1)
//   out[d] = dinv[d]*Sum_{e:s->d}( s[src]*dinv[src] ) + dinv[d]^2*s[d] + c
//
// R3: ONE cooperative kernel, 3 grid syncs, zero extra dispatches.
// R1->R2 showed atomics were never the bottleneck (CAS->native: -3 us of 109);
// the profile top-5 is 100% harness poison fills. Remaining suspects are
// per-dispatch overhead (5 graph nodes) vs fill floor — both fixed/measured
// by collapsing to a single dispatch.
//
// Phases:
//  P0: zero deg[50k]+acc[50k]; waves 0..100 fold w (W1@Wh) and c
//  P1: deg[dst]++ per edge (native u32 atomic) + wave-per-node score s[i]=x[i].w
//  P2: acc[dst] += s[src]*rsqrt(deg[src]+1)   (native f32 atomic)
//  P3: out[i] = dinv*acc[i] + dinv^2*s[i] + c

#define N_NODES 50000
#define F_IN    100
#define H_DIM   1024
#define N_EDGES 200000
#define GRID    512
#define BLK     256

__global__ void __launch_bounds__(BLK)
k_gcn_all(const float* __restrict__ x,   const int* __restrict__ ei,
          const float* __restrict__ W1,  const float* __restrict__ b1,
          const float* __restrict__ Wh,  const float* __restrict__ bh,
          float* __restrict__ out,
          float* __restrict__ wbuf, float* __restrict__ cbuf,
          unsigned* __restrict__ deg, float* __restrict__ acc,
          float* __restrict__ sbuf)
{
    cg::grid_group grid = cg::this_grid();
    const int tid   = blockIdx.x * BLK + threadIdx.x;   // 0..131071
    const int nthr  = GRID * BLK;                        // 131072
    const int gwave = tid >> 6;                          // 0..2047
    const int lane  = tid & 63;
    const int nwave = nthr >> 6;                         // 2048
    const int* src  = ei;
    const int* dst  = ei + N_EDGES;

    // ---- P0: zero deg+acc (contiguous 2*N words); fold w,c on waves 0..100
    {
        unsigned* z = deg;                               // deg | acc contiguous
        for (int i = tid; i < 2 * N_NODES; i += nthr) z[i] = 0u;
        if (gwave <= 100) {
            const float* row = (gwave < 100) ? (W1 + (size_t)gwave * H_DIM) : b1;
            float s = 0.0f;
            #pragma unroll
            for (int k = 0; k < H_DIM / 64; ++k) {
                const int h = lane + 64 * k;
                s += row[h] * Wh[h];
            }
            #pragma unroll
            for (int off = 32; off > 0; off >>= 1) s += __shfl_down(s, off, 64);
            if (lane == 0) {
                if (gwave < 100) wbuf[gwave] = s;
                else             cbuf[0]     = s + bh[0];
            }
        }
    }
    grid.sync();

    // ---- P1: degree count + per-node scores (independent; fused)
    for (int e = tid; e < N_EDGES; e += nthr)
        atomicAdd(&deg[dst[e]], 1u);                     // native u32 atomic

    for (int i = gwave; i < N_NODES; i += nwave) {
        const float* row = x + (size_t)i * F_IN;
        float s = row[lane] * wbuf[lane];                          // 0..63
        if (lane < F_IN - 64) s += row[64 + lane] * wbuf[64 + lane]; // 64..99
        #pragma unroll
        for (int off = 32; off > 0; off >>= 1) s += __shfl_down(s, off, 64);
        if (lane == 0) sbuf[i] = s;
    }
    grid.sync();

    // ---- P2: edge scatter with per-source normalization
    for (int e = tid; e < N_EDGES; e += nthr) {
        const int sn = src[e], dn = dst[e];
        const float us = sbuf[sn] * rsqrtf((float)deg[sn] + 1.0f);
        unsafeAtomicAdd(&acc[dn], us);                   // native f32 atomic
    }
    grid.sync();

    // ---- P3: finalize
    const float cv = cbuf[0];
    for (int i = tid; i < N_NODES; i += nthr) {
        const float dv = rsqrtf((float)deg[i] + 1.0f);
        out[i] = dv * acc[i] + dv * dv * sbuf[i] + cv;
    }
}

extern "C" void kernel_launch(void* const* d_in, const int* in_sizes, int n_in,
                              void* d_out, int out_size, void* d_ws, size_t ws_size,
                              hipStream_t stream)
{
    const float* x   = (const float*)d_in[0];   // (50000,100)
    const int*   ei  = (const int*)  d_in[1];   // (2,200000)
    const float* W1  = (const float*)d_in[2];   // (100,1024)
    const float* b1  = (const float*)d_in[3];   // (1024,)
    const float* Wh  = (const float*)d_in[4];   // (1024,)
    const float* bh  = (const float*)d_in[5];   // (1,)
    float*       out = (float*)d_out;           // (50000,)

    // ws layout (4B units): w[100] c[1] pad->128 | deg[50000] acc[50000] | s[50000]
    float*    ws_f = (float*)d_ws;
    float*    wbuf = ws_f;
    float*    cbuf = ws_f + 100;
    unsigned* deg  = (unsigned*)(ws_f + 128);
    float*    acc  = ws_f + 128 + N_NODES;
    float*    sbuf = ws_f + 128 + 2 * N_NODES;

    void* args[] = { (void*)&x,   (void*)&ei,   (void*)&W1, (void*)&b1,
                     (void*)&Wh,  (void*)&bh,   (void*)&out,
                     (void*)&wbuf,(void*)&cbuf, (void*)&deg,
                     (void*)&acc, (void*)&sbuf };
    hipLaunchCooperativeKernel((const void*)k_gcn_all, dim3(GRID), dim3(BLK),
                               args, 0, stream);
}

// Round 4
// 103.495 us; speedup vs baseline: 2.6680x; 2.6680x over previous
//
#include <hip/hip_runtime.h>

// CriticGCN: out = D^-1/2 (A+I) D^-1/2 (x W1) + b1, then @ W_head + b_head.
// Head folded through the (linear) aggregation:
//   w = W1 @ W_head (100 floats), c = b1.W_head + b_head
//   s[i] = x[i].w ; dinv[i] = rsqrt(deg[i]+1)
//   out[d] = dinv[d]*Sum_{e:s->d}( s[src]*dinv[src] ) + dinv[d]^2*s[d] + c
//
// R4: back to multi-kernel (R3 proved grid.sync costs ~60 us/sync on gfx950 —
// cross-XCD coherence flush; kernel boundary is cheaper). dur_us decomposes as
// [our kernels ~25 us] + [fixed ~84 us harness poison fills]. This round cuts
// the controllable part: 4 graph nodes (zero+fold / deg+score / scatter /
// final), int4/int2 edge-index loads, full-parallel wave-per-node score,
// float4 zero & finalize.

#define N_NODES 50000
#define F_IN    100
#define H_DIM   1024
#define N_EDGES 200000

// K0 — blocks 0..99: w[f] = dot(W1[f,:], W_head); block 100: c = b1.Wh + bh;
//      blocks 101..198: zero deg[50000]|acc[50000] (contiguous) via float4.
__global__ void __launch_bounds__(256)
k0_zero_fold(const float* __restrict__ W1, const float* __restrict__ b1,
             const float* __restrict__ Wh, const float* __restrict__ bh,
             float* __restrict__ w, float* __restrict__ c,
             float4* __restrict__ zero_region)
{
    const int b = blockIdx.x;
    const int t = threadIdx.x;
    if (b <= 100) {
        const float* row = (b < 100) ? (W1 + (size_t)b * H_DIM) : b1;
        float s = 0.0f;
        #pragma unroll
        for (int k = 0; k < H_DIM / 256; ++k) {
            const int h = t + 256 * k;
            s += row[h] * Wh[h];
        }
        #pragma unroll
        for (int off = 32; off > 0; off >>= 1) s += __shfl_down(s, off, 64);
        __shared__ float red[4];
        const int wave = t >> 6, lane = t & 63;
        if (lane == 0) red[wave] = s;
        __syncthreads();
        if (t == 0) {
            const float tot = red[0] + red[1] + red[2] + red[3];
            if (b < 100) w[b] = tot;
            else         *c  = tot + bh[0];
        }
    } else {
        const int g = (b - 101) * 256 + t;           // 0..25087 over 25000 float4
        if (g < (2 * N_NODES) / 4)
            zero_region[g] = make_float4(0.f, 0.f, 0.f, 0.f);
    }
}

// K1 — wave-per-node score s[i] = x[i].w (no stride loop; 12500 blocks), plus
//      deg count: first 50000 threads each take an int4 of 4 dst indices.
__global__ void __launch_bounds__(256)
k1_deg_score(const float* __restrict__ x, const int* __restrict__ ei,
             const float* __restrict__ w,
             unsigned* __restrict__ deg, float* __restrict__ sbuf)
{
    const int tid   = blockIdx.x * 256 + threadIdx.x;
    const int gwave = tid >> 6;
    const int lane  = tid & 63;

    // degree: 4 edges per thread via one int4 load (dst = ei + N_EDGES, 16B-aligned)
    if (tid < N_EDGES / 4) {
        const int4 d4 = ((const int4*)(ei + N_EDGES))[tid];
        atomicAdd(&deg[d4.x], 1u);
        atomicAdd(&deg[d4.y], 1u);
        atomicAdd(&deg[d4.z], 1u);
        atomicAdd(&deg[d4.w], 1u);
    }

    // score: one wave per node
    if (gwave < N_NODES) {
        const float* row = x + (size_t)gwave * F_IN;
        float s = row[lane] * w[lane];                              // 0..63
        if (lane < F_IN - 64) s += row[64 + lane] * w[64 + lane];   // 64..99
        #pragma unroll
        for (int off = 32; off > 0; off >>= 1) s += __shfl_down(s, off, 64);
        if (lane == 0) sbuf[gwave] = s;
    }
}

// K2 — edge scatter: acc[dst] += s[src]*rsqrt(deg[src]+1). 2 edges/thread via
//      int2 loads (balance vector loads vs gather-latency parallelism).
__global__ void __launch_bounds__(256)
k2_scatter(const int* __restrict__ ei, const unsigned* __restrict__ deg,
           const float* __restrict__ sbuf, float* __restrict__ acc)
{
    const int g = blockIdx.x * 256 + threadIdx.x;    // 0..99999 over int2 pairs
    if (g >= N_EDGES / 2) return;
    const int2 s2 = ((const int2*)ei)[g];
    const int2 d2 = ((const int2*)(ei + N_EDGES))[g];
    const float u0 = sbuf[s2.x] * rsqrtf((float)deg[s2.x] + 1.0f);
    const float u1 = sbuf[s2.y] * rsqrtf((float)deg[s2.y] + 1.0f);
    unsafeAtomicAdd(&acc[d2.x], u0);
    unsafeAtomicAdd(&acc[d2.y], u1);
}

// K3 — finalize, float4: out[i] = dinv*acc[i] + dinv^2*s[i] + c
__global__ void __launch_bounds__(256)
k3_final(const uint4* __restrict__ deg4, const float4* __restrict__ acc4,
         const float4* __restrict__ s4, const float* __restrict__ c,
         float4* __restrict__ out4)
{
    const int g = blockIdx.x * 256 + threadIdx.x;    // 0..12499 float4 groups
    if (g >= N_NODES / 4) return;
    const uint4  d = deg4[g];
    const float4 a = acc4[g];
    const float4 s = s4[g];
    const float  cv = c[0];
    float4 o;
    float dv;
    dv  = rsqrtf((float)d.x + 1.0f); o.x = dv * a.x + dv * dv * s.x + cv;
    dv  = rsqrtf((float)d.y + 1.0f); o.y = dv * a.y + dv * dv * s.y + cv;
    dv  = rsqrtf((float)d.z + 1.0f); o.z = dv * a.z + dv * dv * s.z + cv;
    dv  = rsqrtf((float)d.w + 1.0f); o.w = dv * a.w + dv * dv * s.w + cv;
    out4[g] = o;
}

extern "C" void kernel_launch(void* const* d_in, const int* in_sizes, int n_in,
                              void* d_out, int out_size, void* d_ws, size_t ws_size,
                              hipStream_t stream)
{
    const float* x   = (const float*)d_in[0];   // (50000,100)
    const int*   ei  = (const int*)  d_in[1];   // (2,200000)
    const float* W1  = (const float*)d_in[2];   // (100,1024)
    const float* b1  = (const float*)d_in[3];   // (1024,)
    const float* Wh  = (const float*)d_in[4];   // (1024,)
    const float* bh  = (const float*)d_in[5];   // (1,)
    float*       out = (float*)d_out;           // (50000,)

    // ws layout (4B units): w[100] c[1] pad->128 | deg[50000] acc[50000] | s[50000]
    float*    ws_f = (float*)d_ws;
    float*    w    = ws_f;
    float*    c    = ws_f + 100;
    unsigned* deg  = (unsigned*)(ws_f + 128);
    float*    acc  = ws_f + 128 + N_NODES;
    float*    sbuf = ws_f + 128 + 2 * N_NODES;

    // K0: fold (101 blocks) + zero deg/acc (98 blocks; 25000 float4)
    k0_zero_fold<<<199, 256, 0, stream>>>(W1, b1, Wh, bh, w, c, (float4*)deg);
    // K1: deg count (int4, first 50000 threads) + wave-per-node score
    k1_deg_score<<<(N_NODES * 64 + 255) / 256, 256, 0, stream>>>(x, ei, w, deg, sbuf);
    // K2: edge scatter (int2, 2 edges/thread)
    k2_scatter<<<(N_EDGES / 2 + 255) / 256, 256, 0, stream>>>(ei, deg, sbuf, acc);
    // K3: finalize (float4)
    k3_final<<<(N_NODES / 4 + 255) / 256, 256, 0, stream>>>(
        (const uint4*)deg, (const float4*)acc, (const float4*)sbuf, c, (float4*)out);
}

// Round 5
// 102.843 us; speedup vs baseline: 2.6849x; 1.0063x over previous
//
#include <hip/hip_runtime.h>

// CriticGCN: out = D^-1/2 (A+I) D^-1/2 (x W1) + b1, then @ W_head + b_head.
// Head folded through the (linear) aggregation:
//   w = W1 @ W_head (100 floats), c = b1.W_head + b_head
//   s[i] = x[i].w ; dinv[i] = rsqrt(deg[i]+1)
//   out[d] = c + dinv[d]^2 s[d] + Sum_{e:s->d} dinv[s] dinv[d] s[s]
//
// R5: 3 kernels (was 4). Session decomposition: dur_us = [our ~19 us] +
// [fixed ~84 us harness poison fills]. The finalize kernel is eliminated by
// seeding out[i]=c in K1 (c ready after K0; deg isn't, so dinv terms move to
// K2) and scattering normalized edge + self terms directly into out with
// native f32 atomics. acc buffer gone; K0 zero region halves.
//
//   K0: fold w = W1@Wh, c = b1.Wh + bh   (101 blocks) | zero deg (49 blocks)
//   K1: deg[dst]++ (int4, 50k threads) | seed out=c (float4) | score waves
//   K2: out[dst] += s[src]*dinv[src]*dinv[dst] per edge | out[i] += dinv^2 s[i]

#define N_NODES 50000
#define F_IN    100
#define H_DIM   1024
#define N_EDGES 200000

__global__ void __launch_bounds__(256)
k0_fold_zero(const float* __restrict__ W1, const float* __restrict__ b1,
             const float* __restrict__ Wh, const float* __restrict__ bh,
             float* __restrict__ w, float* __restrict__ c,
             float4* __restrict__ deg_zero)
{
    const int b = blockIdx.x;
    const int t = threadIdx.x;
    if (b <= 100) {
        const float* row = (b < 100) ? (W1 + (size_t)b * H_DIM) : b1;
        float s = 0.0f;
        #pragma unroll
        for (int k = 0; k < H_DIM / 256; ++k) {
            const int h = t + 256 * k;
            s += row[h] * Wh[h];
        }
        #pragma unroll
        for (int off = 32; off > 0; off >>= 1) s += __shfl_down(s, off, 64);
        __shared__ float red[4];
        const int wave = t >> 6, lane = t & 63;
        if (lane == 0) red[wave] = s;
        __syncthreads();
        if (t == 0) {
            const float tot = red[0] + red[1] + red[2] + red[3];
            if (b < 100) w[b] = tot;
            else         *c  = tot + bh[0];
        }
    } else {
        const int g = (b - 101) * 256 + t;           // 12500 float4 = deg[50000]
        if (g < N_NODES / 4)
            deg_zero[g] = make_float4(0.f, 0.f, 0.f, 0.f);
    }
}

// K1 — three independent jobs in one dispatch (12500 blocks):
//   tid < 50000            : deg[dst]++, 4 edges/thread via int4
//   tid in [50000, 62500)  : out[i..i+3] = c (float4 seed)
//   every wave (gwave<50k) : s[i] = x[i].w  (wave per node, coalesced rows)
__global__ void __launch_bounds__(256)
k1_deg_seed_score(const float* __restrict__ x, const int* __restrict__ ei,
                  const float* __restrict__ w, const float* __restrict__ c,
                  unsigned* __restrict__ deg, float* __restrict__ sbuf,
                  float4* __restrict__ out4)
{
    const int tid   = blockIdx.x * 256 + threadIdx.x;
    const int gwave = tid >> 6;
    const int lane  = tid & 63;

    if (tid < N_EDGES / 4) {                          // 50000 threads
        const int4 d4 = ((const int4*)(ei + N_EDGES))[tid];
        atomicAdd(&deg[d4.x], 1u);
        atomicAdd(&deg[d4.y], 1u);
        atomicAdd(&deg[d4.z], 1u);
        atomicAdd(&deg[d4.w], 1u);
    } else if (tid < N_EDGES / 4 + N_NODES / 4) {     // 12500 threads
        const float cv = c[0];
        out4[tid - N_EDGES / 4] = make_float4(cv, cv, cv, cv);
    }

    if (gwave < N_NODES) {
        const float* row = x + (size_t)gwave * F_IN;
        float s = row[lane] * w[lane];                              // 0..63
        if (lane < F_IN - 64) s += row[64 + lane] * w[64 + lane];   // 64..99
        #pragma unroll
        for (int off = 32; off > 0; off >>= 1) s += __shfl_down(s, off, 64);
        if (lane == 0) sbuf[gwave] = s;
    }
}

// K2 — scatter directly into out (seeded with c by K1):
//   tid < 100000           : 2 edges via int2: out[dst] += s[src]*dinv[src]*dinv[dst]
//   tid in [100000,150000) : self term out[i] += dinv[i]^2 * s[i]
__global__ void __launch_bounds__(256)
k2_scatter(const int* __restrict__ ei, const unsigned* __restrict__ deg,
           const float* __restrict__ sbuf, float* __restrict__ out)
{
    const int tid = blockIdx.x * 256 + threadIdx.x;
    if (tid < N_EDGES / 2) {
        const int2 s2 = ((const int2*)ei)[tid];
        const int2 d2 = ((const int2*)(ei + N_EDGES))[tid];
        const float u0 = sbuf[s2.x] * rsqrtf((float)deg[s2.x] + 1.0f)
                                    * rsqrtf((float)deg[d2.x] + 1.0f);
        const float u1 = sbuf[s2.y] * rsqrtf((float)deg[s2.y] + 1.0f)
                                    * rsqrtf((float)deg[d2.y] + 1.0f);
        unsafeAtomicAdd(&out[d2.x], u0);
        unsafeAtomicAdd(&out[d2.y], u1);
    } else if (tid < N_EDGES / 2 + N_NODES) {
        const int i = tid - N_EDGES / 2;
        const float dv = rsqrtf((float)deg[i] + 1.0f);
        unsafeAtomicAdd(&out[i], dv * dv * sbuf[i]);
    }
}

extern "C" void kernel_launch(void* const* d_in, const int* in_sizes, int n_in,
                              void* d_out, int out_size, void* d_ws, size_t ws_size,
                              hipStream_t stream)
{
    const float* x   = (const float*)d_in[0];   // (50000,100)
    const int*   ei  = (const int*)  d_in[1];   // (2,200000)
    const float* W1  = (const float*)d_in[2];   // (100,1024)
    const float* b1  = (const float*)d_in[3];   // (1024,)
    const float* Wh  = (const float*)d_in[4];   // (1024,)
    const float* bh  = (const float*)d_in[5];   // (1,)
    float*       out = (float*)d_out;           // (50000,)

    // ws layout (4B units): w[100] c[1] pad->128 | deg[50000] | s[50000]
    float*    ws_f = (float*)d_ws;
    float*    w    = ws_f;
    float*    c    = ws_f + 100;
    unsigned* deg  = (unsigned*)(ws_f + 128);
    float*    sbuf = ws_f + 128 + N_NODES;

    // K0: fold w,c (101 blocks) + zero deg (49 blocks)
    k0_fold_zero<<<101 + (N_NODES / 4 + 255) / 256, 256, 0, stream>>>(
        W1, b1, Wh, bh, w, c, (float4*)deg);
    // K1: deg count + seed out=c + wave-per-node score
    k1_deg_seed_score<<<(N_NODES * 64 + 255) / 256, 256, 0, stream>>>(
        x, ei, w, c, deg, sbuf, (float4*)out);
    // K2: normalized edge scatter + self term, directly into out
    k2_scatter<<<(N_EDGES / 2 + N_NODES + 255) / 256, 256, 0, stream>>>(
        ei, deg, sbuf, out);
}